// Round 7
// baseline (696.873 us; speedup 1.0000x reference)
//
#include <hip/hip_runtime.h>
#include <hip/hip_bf16.h>
#include <cstdint>
#include <cstddef>

// ---------------------------------------------------------------------------
// EncoderBlockWithMemory on MI355X (gfx950). bf16-or-fp32 inputs (runtime
// detect), bf16 MFMA math, fp32 accumulate.
// R12: gemm_bt gains 3-deep rolling prefetch: triple-buffered LDS
// (3x16KB=48KB, still 3 blocks/CU), stage tile t+2 during iter t, wait
// ladder vmcnt(8)/(4)/(0) -> each stage gets TWO K-steps to land instead of
// one (L2/HBM latency 200-900cy vs ~240cy/step of resident compute).
// Everything else frozen from R11 (648.7us): merged-QKV mode-5 launch,
// __launch_bounds__(256,3), chunk-XOR swizzle, XCD-chunked remap; flash =
// R8 verified (128us).
// ---------------------------------------------------------------------------

typedef __attribute__((ext_vector_type(8))) short short8;
typedef __attribute__((ext_vector_type(4))) float floatx4;
typedef __attribute__((ext_vector_type(4))) unsigned short ushort4v;

#define NB   4
#define SEQ  2048
#define DM   1024
#define DKH  64
#define TT   2080
#define DFF  4096
#define NMEM 32

static __device__ __forceinline__ float bu2f(unsigned short u) {
  return __uint_as_float(((unsigned int)u) << 16);
}
static __device__ __forceinline__ unsigned short f2bu(float x) {
  __hip_bfloat16 h = __float2bfloat16(x);
  return *reinterpret_cast<unsigned short*>(&h);
}
static __device__ __forceinline__ float fast_exp2(float x) {
#if __has_builtin(__builtin_amdgcn_exp2f)
  return __builtin_amdgcn_exp2f(x);
#else
  return exp2f(x);
#endif
}
static __device__ __forceinline__ void async16(const void* g, void* l) {
  __builtin_amdgcn_global_load_lds(
      (const __attribute__((address_space(1))) void*)g,
      (__attribute__((address_space(3))) void*)l, 16, 0, 0);
}

// --------------------------- merged prep kernel ----------------------------
#define PREP_X   8192
#define PREP_MT  (PREP_X + 32)
#define PREP_SM  (PREP_MT + 9)
#define PREP_T   (PREP_SM + 3072)

__global__ __launch_bounds__(256) void prep(
    const void* __restrict__ x,   const void* __restrict__ memtok,
    const void* __restrict__ wq,  const void* __restrict__ wk,
    const void* __restrict__ wv,  const void* __restrict__ wo,
    const void* __restrict__ fw1, const void* __restrict__ fw2,
    const void* __restrict__ ln1a, const void* __restrict__ ln1b,
    const void* __restrict__ ln2a, const void* __restrict__ ln2b,
    const void* __restrict__ fb1, const void* __restrict__ fb2,
    unsigned short* __restrict__ xb, unsigned short* __restrict__ MT,
    unsigned short* __restrict__ Wtq, unsigned short* __restrict__ Wtk,
    unsigned short* __restrict__ Wtv, unsigned short* __restrict__ Wto,
    unsigned short* __restrict__ Wt1, unsigned short* __restrict__ Wt2,
    unsigned short* __restrict__ L1A, unsigned short* __restrict__ L1B,
    unsigned short* __restrict__ L2A, unsigned short* __restrict__ L2B,
    unsigned short* __restrict__ FB1, unsigned short* __restrict__ FB2,
    int* __restrict__ FLAG)
{
  const int tid = threadIdx.x;
  const unsigned short probe = ((const unsigned short*)x)[tid & 63];
  const unsigned e = (probe >> 7) & 0xFF;
  const bool ok = (e == 0) || (e >= 100 && e <= 141);
  const int flag = (__ballot(!ok) != 0ULL) ? 1 : 0;
  const int bid = blockIdx.x;
  if (bid == 0 && tid == 0) *FLAG = flag;

  if (bid < PREP_T && bid >= PREP_SM) {
    const int tb = bid - PREP_SM;
    const void* in; unsigned short* outp; int R, C, tx, ty;
    if (tb < 1024) {
      const int w = tb >> 8, lt = tb & 255;
      in = (w == 0) ? wq : (w == 1) ? wk : (w == 2) ? wv : wo;
      outp = (w == 0) ? Wtq : (w == 1) ? Wtk : (w == 2) ? Wtv : Wto;
      R = DM; C = DM; tx = lt & 15; ty = lt >> 4;
    } else if (tb < 2048) {
      const int lt = tb - 1024;
      in = fw1; outp = Wt1; R = DM; C = DFF; tx = lt & 63; ty = lt >> 6;
    } else {
      const int lt = tb - 2048;
      in = fw2; outp = Wt2; R = DFF; C = DM; tx = lt & 15; ty = lt >> 4;
    }
    __shared__ unsigned short tile[64][65];
    const int r0 = ty << 6, c0 = tx << 6;
    const int lr = tid >> 2, lc = (tid & 3) << 4;
    if (flag) {
      const float* ip = (const float*)in + (size_t)(r0 + lr) * C + c0 + lc;
#pragma unroll
      for (int q = 0; q < 16; q += 4) {
        floatx4 f = *(const floatx4*)(ip + q);
        tile[lr][lc+q+0] = f2bu(f[0]); tile[lr][lc+q+1] = f2bu(f[1]);
        tile[lr][lc+q+2] = f2bu(f[2]); tile[lr][lc+q+3] = f2bu(f[3]);
      }
    } else {
      const unsigned short* ip = (const unsigned short*)in + (size_t)(r0 + lr) * C + c0 + lc;
#pragma unroll
      for (int q = 0; q < 16; q += 4) {
        ushort4v a = *(const ushort4v*)(ip + q);
        tile[lr][lc+q+0] = a.x; tile[lr][lc+q+1] = a.y;
        tile[lr][lc+q+2] = a.z; tile[lr][lc+q+3] = a.w;
      }
    }
    __syncthreads();
    unsigned short* op = outp + (size_t)(c0 + lr) * R + r0 + lc;
#pragma unroll
    for (int q = 0; q < 16; q += 4) {
      ushort4v a;
      a.x = tile[lc+q+0][lr]; a.y = tile[lc+q+1][lr];
      a.z = tile[lc+q+2][lr]; a.w = tile[lc+q+3][lr];
      *(ushort4v*)(op + q) = a;
    }
    return;
  }

  const void* src; unsigned short* dst; int base;
  if (bid < PREP_X)      { src = x;      dst = xb; base = bid * 1024; }
  else if (bid < PREP_MT){ src = memtok; dst = MT; base = (bid - PREP_X) * 1024; }
  else {
    const int s = bid - PREP_MT; base = 0;
    if      (s == 0) { src = ln1a; dst = L1A; }
    else if (s == 1) { src = ln1b; dst = L1B; }
    else if (s == 2) { src = ln2a; dst = L2A; }
    else if (s == 3) { src = ln2b; dst = L2B; }
    else if (s <= 7) { src = fb1;  dst = FB1; base = (s - 4) * 1024; }
    else             { src = fb2;  dst = FB2; }
  }
  const int i = base + tid * 4;
  if (flag) {
    const float* s4 = (const float*)src + i;
    ushort4v o;
    o.x = f2bu(s4[0]); o.y = f2bu(s4[1]); o.z = f2bu(s4[2]); o.w = f2bu(s4[3]);
    *(ushort4v*)&dst[i] = o;
  } else {
    *(ushort4v*)&dst[i] = *(const ushort4v*)&((const unsigned short*)src)[i];
  }
}

// ---------------------------------------------------------------------------
// gemm_bt: C[M,N] = A[M,K](lda) @ Bt[N,K](ldbt)^T (+bias)(relu)(+resid).
// BK=32, 128x128 tile, 4 waves, __launch_bounds__(256,3) -> 3 blocks/CU.
// R12: TRIPLE-buffered LDS (48KB) with 3-deep rolling prefetch:
//   iter t: [if t+2<nk] stage(buf[(t+2)%3], t+2); vmcnt(8)   (2 stages fly)
//           [elif t+1<nk] vmcnt(4)  [else] vmcnt(0)
//           barrier; 16 MFMA from buf[t%3]; lgkmcnt(0); barrier
// stage(t+2) writes buf[(t-1)%3], freed at iter t-1's release barrier.
// Chunk-XOR swizzle (pre-swizzled stage src + XOR'd frag read); XCD-chunked
// remap (all grids nwg%8==0).
// modes: 0 bf16 out  3 fp32 out  4 final d_out (dtype per *dt)
//        5 merged QKV col-sector epilogue (Q plain / K remap / V^T remap)
// ---------------------------------------------------------------------------
__global__ __launch_bounds__(256, 3) void gemm_bt(
    const unsigned short* __restrict__ A, int lda,
    const unsigned short* __restrict__ Bt, int ldbt,
    const unsigned short* __restrict__ bias,
    const unsigned short* __restrict__ resid_b,
    const float* __restrict__ resid_f,
    void* __restrict__ outp, void* __restrict__ outp2, void* __restrict__ outp3,
    int M, int N, int K, int relu, int mode, const int* __restrict__ dt)
{
  __shared__ __align__(16) unsigned short As[3][128 * 32];
  __shared__ __align__(16) unsigned short Bs[3][128 * 32];

  const int tid  = threadIdx.x;
  const int wave = tid >> 6;
  const int lane = tid & 63;
  const int quad = lane >> 4;
  const int lr   = lane & 15;
  const int wm   = (wave >> 1) * 64;
  const int wn   = (wave & 1) * 64;

  const int gx  = gridDim.x;
  const int nwg = gx * gridDim.y;
  int wg = blockIdx.y * gx + blockIdx.x;
  wg = (wg & 7) * (nwg >> 3) + (wg >> 3);
  const int by = wg / gx;
  const int bx = wg - by * gx;
  const int m0 = by * 128;
  const int n0 = bx * 128;

  floatx4 acc[4][4];
#pragma unroll
  for (int i = 0; i < 4; ++i)
#pragma unroll
    for (int j = 0; j < 4; ++j) { floatx4 z = {0.f, 0.f, 0.f, 0.f}; acc[i][j] = z; }

  const int srow = lane >> 2;
  const int skof = (((lane & 3) ^ ((lane >> 3) & 3))) * 8;
  const int fsw  = (lr >> 1) & 3;

  auto stage = [&](int buf, int kk) {
#pragma unroll
    for (int i = 0; i < 2; ++i) {
      const int rr = wave * 32 + i * 16;
      const int r  = rr + srow;
      int gr = m0 + r; gr = gr < M ? gr : (M - 1);
      async16(A  + (size_t)gr * lda + kk + skof, &As[buf][rr * 32]);
      const int gn = n0 + r;
      async16(Bt + (size_t)gn * ldbt + kk + skof, &Bs[buf][rr * 32]);
    }
  };

  const int nk = K >> 5;
  stage(0, 0);
  if (nk > 1) stage(1, 32);
  int cur = 0;
  for (int it = 0; it < nk; ++it) {
    if (it + 2 < nk) {
      int sb = cur + 2; if (sb >= 3) sb -= 3;
      stage(sb, (it + 2) << 5);
      asm volatile("s_waitcnt vmcnt(8)" ::: "memory");   // tile t landed
    } else if (it + 1 < nk) {
      asm volatile("s_waitcnt vmcnt(4)" ::: "memory");
    } else {
      asm volatile("s_waitcnt vmcnt(0)" ::: "memory");
    }
    __builtin_amdgcn_s_barrier();

    const unsigned short* Ab = &As[cur][0];
    const unsigned short* Bb = &Bs[cur][0];
    short8 af[4], bfr[4];
#pragma unroll
    for (int mi = 0; mi < 4; ++mi)
      af[mi]  = *(const short8*)&Ab[(wm + mi * 16 + lr) * 32 + ((quad ^ fsw) * 8)];
#pragma unroll
    for (int ni = 0; ni < 4; ++ni)
      bfr[ni] = *(const short8*)&Bb[(wn + ni * 16 + lr) * 32 + ((quad ^ fsw) * 8)];
#pragma unroll
    for (int mi = 0; mi < 4; ++mi)
#pragma unroll
      for (int ni = 0; ni < 4; ++ni)
        acc[mi][ni] = __builtin_amdgcn_mfma_f32_16x16x32_bf16(af[mi], bfr[ni], acc[mi][ni], 0, 0, 0);

    asm volatile("s_waitcnt lgkmcnt(0)" ::: "memory");
    __builtin_amdgcn_s_barrier();
    ++cur; if (cur == 3) cur = 0;
  }

  if (mode == 5) {
    // merged QKV: sector by output column block (wave-uniform; 128-col tiles
    // never straddle a 1024 boundary, and each wave spans 64 cols).
    const int cb     = n0 + wn;
    const int sector = cb >> 10;
    const int clb    = cb & 1023;
    unsigned short* Qo = (unsigned short*)outp;
    unsigned short* Ko = (unsigned short*)outp2;
    unsigned short* Vo = (unsigned short*)outp3;
#pragma unroll
    for (int mi = 0; mi < 4; ++mi) {
      const int rb = m0 + wm + mi * 16 + quad * 4;
#pragma unroll
      for (int ni = 0; ni < 4; ++ni) {
        const int col = clb + ni * 16 + lr;
        if (sector == 0) {
#pragma unroll
          for (int rg = 0; rg < 4; ++rg) {
            const int r = rb + rg;
            if (r < NB * SEQ) Qo[(size_t)r * DM + col] = f2bu(acc[mi][ni][rg]);
          }
        } else if (sector == 1) {
#pragma unroll
          for (int rg = 0; rg < 4; ++rg) {
            const int r = rb + rg;
            if (r >= M) continue;
            const int row2 = (r < NB * SEQ) ? ((r >> 11) * TT + NMEM + (r & (SEQ - 1)))
                                            : (r - NB * SEQ);
            Ko[(size_t)row2 * DM + col] = f2bu(acc[mi][ni][rg]);
          }
        } else {
          if (rb < M) {                     // M%4==0 -> rb+3 < M too
            int bb, t;
            if (rb < NB * SEQ) { bb = rb >> 11; t = NMEM + (rb & (SEQ - 1)); }
            else               { bb = 0;        t = rb - NB * SEQ; }
            ushort4v pk;
            pk.x = f2bu(acc[mi][ni][0]); pk.y = f2bu(acc[mi][ni][1]);
            pk.z = f2bu(acc[mi][ni][2]); pk.w = f2bu(acc[mi][ni][3]);
            *(ushort4v*)(Vo + ((size_t)bb * DM + col) * TT + t) = pk;
          }
        }
      }
    }
    return;
  }

  const int ofp32 = (mode == 4 && dt) ? *dt : 0;
#pragma unroll
  for (int mi = 0; mi < 4; ++mi) {
    const int rb = m0 + wm + mi * 16 + quad * 4;
#pragma unroll
    for (int ni = 0; ni < 4; ++ni) {
      const int col = n0 + wn + ni * 16 + lr;
      const float bv = bias ? bu2f(bias[col]) : 0.0f;
#pragma unroll
      for (int rg = 0; rg < 4; ++rg) {
        const int r = rb + rg;
        if (r >= M) continue;
        float v = acc[mi][ni][rg] + bv;
        if (relu) v = fmaxf(v, 0.0f);
        if (resid_b) v += bu2f(resid_b[(size_t)r * N + col]);
        if (resid_f) v += resid_f[(size_t)r * N + col];
        const size_t idx = (size_t)r * N + col;
        if (mode == 3)       ((float*)outp)[idx] = v;
        else if (mode == 4) {
          if (ofp32) ((float*)outp)[idx] = v;
          else       ((unsigned short*)outp)[idx] = f2bu(v);
        } else               ((unsigned short*)outp)[idx] = f2bu(v);
      }
    }
  }
}

// ---------------------------------------------------------------------------
// Flash attention (R8, verified): K/V double-buffer, counted vmcnt(4),
// setprio around MFMA clusters, XCD-aware 1D block mapping.
// ---------------------------------------------------------------------------
#define PSTR 72

__global__ __launch_bounds__(256, 3) void flash_attn(
    const unsigned short* __restrict__ Q,
    const unsigned short* __restrict__ Kb,
    const unsigned short* __restrict__ Vtb,
    unsigned short* __restrict__ ctx)
{
  __shared__ __align__(16) unsigned short Ks[2][64 * 64];
  __shared__ __align__(16) unsigned short Vs[2][64 * 64];
  __shared__ __align__(16) unsigned short Ps[128 * PSTR];

  const int tid  = threadIdx.x;
  const int wave = tid >> 6;
  const int lane = tid & 63;
  const int quad = lane >> 4;
  const int lr   = lane & 15;

  const int i    = blockIdx.x;
  const int pair = (i & 7) * 8 + (i >> 7);
  const int q0   = ((i >> 3) & 15) * 128;
  const int b    = pair >> 4;
  const int h    = pair & 15;

  const unsigned short* Qb  = Q   + ((size_t)(b * SEQ + q0)) * DM + h * DKH;
  const unsigned short* Kbp = Kb  + ((size_t)b * TT) * DM + h * DKH;
  const unsigned short* Vbp = Vtb + ((size_t)(b * DM + h * DKH)) * TT;

  short8 aq[2][2];
#pragma unroll
  for (int mi = 0; mi < 2; ++mi)
#pragma unroll
    for (int ks = 0; ks < 2; ++ks)
      aq[mi][ks] = *(const short8*)(Qb + (size_t)(wave * 32 + mi * 16 + lr) * DM
                                       + ks * 32 + quad * 8);

  const int srl = lane >> 3;
  const int swc = (lane & 7) ^ srl;

  floatx4 O[2][4], Osum[2];
#pragma unroll
  for (int mi = 0; mi < 2; ++mi) {
    floatx4 z = {0.f, 0.f, 0.f, 0.f};
    Osum[mi] = z;
#pragma unroll
    for (int ni = 0; ni < 4; ++ni) O[mi][ni] = z;
  }
  short8 ones;
#pragma unroll
  for (int i2 = 0; i2 < 8; ++i2) ones[i2] = (short)0x3F80;

  const float SC = 0.125f * 1.4426950408889634f;

  auto stageKV = [&](int buf, int t0s) {
#pragma unroll
    for (int i2 = 0; i2 < 2; ++i2) {
      const int rr = (wave * 2 + i2) * 8 + srl;
      int tg = t0s + rr; tg = tg < TT ? tg : (TT - 1);
      async16(Kbp + (size_t)tg * DM + swc * 8, &Ks[buf][(wave * 2 + i2) * 512]);
      int ts = t0s + swc * 8; ts = ts <= (TT - 8) ? ts : (TT - 8);
      async16(Vbp + (size_t)rr * TT + ts, &Vs[buf][(wave * 2 + i2) * 512]);
    }
  };

  stageKV(0, 0);
  int cur = 0;

  for (int t0 = 0; t0 < TT; t0 += 64) {
    if (t0 + 64 < TT) {
      stageKV(cur ^ 1, t0 + 64);
      asm volatile("s_waitcnt vmcnt(4)" ::: "memory");
    } else {
      asm volatile("s_waitcnt vmcnt(0)" ::: "memory");
    }
    __builtin_amdgcn_s_barrier();

    floatx4 sc4[2][4];
#pragma unroll
    for (int mi = 0; mi < 2; ++mi)
#pragma unroll
      for (int ni = 0; ni < 4; ++ni) { floatx4 z = {0.f, 0.f, 0.f, 0.f}; sc4[mi][ni] = z; }
#pragma unroll
    for (int ks = 0; ks < 2; ++ks) {
      short8 bk[4];
#pragma unroll
      for (int ni = 0; ni < 4; ++ni) {
        const int row = ni * 16 + lr;
        bk[ni] = *(const short8*)&Ks[cur][row * 64 + (((ks * 4 + quad) ^ (row & 7)) * 8)];
      }
      __builtin_amdgcn_s_setprio(1);
#pragma unroll
      for (int mi = 0; mi < 2; ++mi)
#pragma unroll
        for (int ni = 0; ni < 4; ++ni)
          sc4[mi][ni] = __builtin_amdgcn_mfma_f32_16x16x32_bf16(aq[mi][ks], bk[ni], sc4[mi][ni], 0, 0, 0);
      __builtin_amdgcn_s_setprio(0);
    }

    bool valid[4];
#pragma unroll
    for (int ni = 0; ni < 4; ++ni) valid[ni] = (t0 + ni * 16 + lr) < TT;

#pragma unroll
    for (int mi = 0; mi < 2; ++mi)
#pragma unroll
      for (int rg = 0; rg < 4; ++rg) {
        const int prow = wave * 32 + mi * 16 + quad * 4 + rg;
#pragma unroll
        for (int ni = 0; ni < 4; ++ni) {
          const float p = valid[ni] ? fast_exp2(sc4[mi][ni][rg] * SC) : 0.0f;
          Ps[prow * PSTR + ni * 16 + lr] =
              (unsigned short)((__float_as_uint(p) + 0x8000u) >> 16);
        }
      }

    __asm__ __volatile__("" ::: "memory");

#pragma unroll
    for (int ks = 0; ks < 2; ++ks) {
      short8 ap[2], bv[4];
#pragma unroll
      for (int mi = 0; mi < 2; ++mi)
        ap[mi] = *(const short8*)&Ps[(wave * 32 + mi * 16 + lr) * PSTR + ks * 32 + quad * 8];
#pragma unroll
      for (int ni = 0; ni < 4; ++ni) {
        const int row = ni * 16 + lr;
        bv[ni] = *(const short8*)&Vs[cur][row * 64 + (((ks * 4 + quad) ^ (row & 7)) * 8)];
      }
      __builtin_amdgcn_s_setprio(1);
#pragma unroll
      for (int mi = 0; mi < 2; ++mi) {
        Osum[mi] = __builtin_amdgcn_mfma_f32_16x16x32_bf16(ap[mi], ones, Osum[mi], 0, 0, 0);
#pragma unroll
        for (int ni = 0; ni < 4; ++ni)
          O[mi][ni] = __builtin_amdgcn_mfma_f32_16x16x32_bf16(ap[mi], bv[ni], O[mi][ni], 0, 0, 0);
      }
      __builtin_amdgcn_s_setprio(0);
    }

    asm volatile("s_waitcnt lgkmcnt(0)" ::: "memory");
    __builtin_amdgcn_s_barrier();
    cur ^= 1;
  }

#pragma unroll
  for (int mi = 0; mi < 2; ++mi)
#pragma unroll
    for (int rg = 0; rg < 4; ++rg) {
      const float inv = 1.0f / Osum[mi][rg];
      const int row = q0 + wave * 32 + mi * 16 + quad * 4 + rg;
#pragma unroll
      for (int ni = 0; ni < 4; ++ni) {
        const int col = h * DKH + ni * 16 + lr;
        ctx[((size_t)(b * SEQ + row)) * DM + col] = f2bu(O[mi][ni][rg] * inv);
      }
    }
}

// ---------------------------------------------------------------------------
__global__ __launch_bounds__(256) void ln_kernel(
    const unsigned short* __restrict__ xin_bf,
    const float* __restrict__ xin_f,
    const unsigned short* __restrict__ memtok,
    const unsigned short* __restrict__ gam,
    const unsigned short* __restrict__ bet,
    unsigned short* __restrict__ outp,
    int rows_main)
{
  const int row = blockIdx.x;
  const int tid = threadIdx.x;
  const int c0  = tid * 4;
  if (row >= rows_main) {
    const int mr = row - rows_main;
    *(ushort4v*)&outp[(size_t)row * DM + c0] =
        *(const ushort4v*)&memtok[(size_t)mr * DM + c0];
    return;
  }
  float v[4];
  if (xin_bf) {
    ushort4v u = *(const ushort4v*)&xin_bf[(size_t)row * DM + c0];
    v[0] = bu2f(u.x); v[1] = bu2f(u.y); v[2] = bu2f(u.z); v[3] = bu2f(u.w);
  } else {
    floatx4 f = *(const floatx4*)&xin_f[(size_t)row * DM + c0];
    v[0] = f[0]; v[1] = f[1]; v[2] = f[2]; v[3] = f[3];
  }
  float s  = v[0] + v[1] + v[2] + v[3];
  float ss = v[0]*v[0] + v[1]*v[1] + v[2]*v[2] + v[3]*v[3];
#pragma unroll
  for (int m = 1; m <= 32; m <<= 1) {
    s  += __shfl_xor(s, m, 64);
    ss += __shfl_xor(ss, m, 64);
  }
  __shared__ float red[8];
  const int wave = tid >> 6, lane = tid & 63;
  if (lane == 0) { red[wave] = s; red[4 + wave] = ss; }
  __syncthreads();
  s  = red[0] + red[1] + red[2] + red[3];
  ss = red[4] + red[5] + red[6] + red[7];
  const float mean = s * (1.0f / 1024.0f);
  float var = (ss - 1024.0f * mean * mean) * (1.0f / 1023.0f);
  var = fmaxf(var, 0.0f);
  const float inv = 1.0f / (sqrtf(var) + 1e-6f);
  ushort4v o;
  o.x = f2bu(bu2f(gam[c0+0]) * (v[0] - mean) * inv + bu2f(bet[c0+0]));
  o.y = f2bu(bu2f(gam[c0+1]) * (v[1] - mean) * inv + bu2f(bet[c0+1]));
  o.z = f2bu(bu2f(gam[c0+2]) * (v[2] - mean) * inv + bu2f(bet[c0+2]));
  o.w = f2bu(bu2f(gam[c0+3]) * (v[3] - mean) * inv + bu2f(bet[c0+3]));
  *(ushort4v*)&outp[(size_t)row * DM + c0] = o;
}

__global__ __launch_bounds__(256) void replicate_mem(
    unsigned short* __restrict__ Kb, unsigned short* __restrict__ Vtb)
{
  const int idx = blockIdx.x * 256 + threadIdx.x;
  const int t = idx >> 10, c = idx & 1023;
  const unsigned short kv = Kb[(size_t)t * DM + c];
  const unsigned short vv = Vtb[(size_t)c * TT + t];
#pragma unroll
  for (int b = 1; b < NB; ++b) {
    Kb[((size_t)b * TT + t) * DM + c] = kv;
    Vtb[((size_t)(b * DM + c)) * TT + t] = vv;
  }
}

__global__ __launch_bounds__(256) void colsum(
    const void* __restrict__ xo, float* __restrict__ acc,
    const int* __restrict__ flag)
{
  const int d  = blockIdx.x * 256 + threadIdx.x;
  const int s0 = blockIdx.y * 256;
  const int b  = blockIdx.z;
  const size_t base = ((size_t)(b * SEQ + s0)) * DM + d;
  float s = 0.0f;
  if (*flag) {
    const float* p = (const float*)xo;
    for (int i = 0; i < 256; ++i) s += p[base + (size_t)i * DM];
  } else {
    const unsigned short* p = (const unsigned short*)xo;
    for (int i = 0; i < 256; ++i) s += bu2f(p[base + (size_t)i * DM]);
  }
  atomicAdd(&acc[b * DM + d], s);
}

__global__ __launch_bounds__(256) void write_mem(
    const float* __restrict__ acc, void* __restrict__ dout,
    const int* __restrict__ flag)
{
  const int idx = blockIdx.x * 256 + threadIdx.x;
  const int b = idx >> 10, d = idx & 1023;
  const float w = acc[idx] * (1.0f / 2048.0f);
  const int f = *flag;
#pragma unroll
  for (int m = 0; m < NMEM; ++m) {
    const size_t off = (size_t)NB * SEQ * DM + ((size_t)(b * NMEM + m)) * DM + d;
    if (f) ((float*)dout)[off] = w;
    else   ((unsigned short*)dout)[off] = f2bu(w);
  }
}

// ---------------------------------------------------------------------------
extern "C" void kernel_launch(void* const* d_in, const int* in_sizes, int n_in,
                              void* d_out, int out_size, void* d_ws, size_t ws_size,
                              hipStream_t stream) {
  const void* x      = d_in[0];
  const void* memtok = d_in[2];
  const void* wq     = d_in[3];
  const void* wk     = d_in[4];
  const void* wv     = d_in[5];
  const void* wo     = d_in[6];
  const void* ln1a   = d_in[7];
  const void* ln1b   = d_in[8];
  const void* ln2a   = d_in[9];
  const void* ln2b   = d_in[10];
  const void* fw1    = d_in[11];
  const void* fb1    = d_in[12];
  const void* fw2    = d_in[13];
  const void* fb2    = d_in[14];

  char* ws = (char*)d_ws;
  constexpr size_t OFF_WT1 = 0;
  constexpr size_t OFF_WT2 = OFF_WT1 + (size_t)DFF * DM * 2;
  constexpr size_t OFF_VT  = OFF_WT2 + (size_t)DM * DFF * 2;
  constexpr size_t SZ_VT   = (size_t)NB * DM * TT * 2;
  constexpr size_t OFF_Q   = OFF_VT + SZ_VT;
  constexpr size_t SZ_Q    = (size_t)NB * SEQ * DM * 2;
  constexpr size_t OFF_K   = OFF_Q + SZ_Q;
  constexpr size_t SZ_K    = (size_t)NB * TT * DM * 2;
  constexpr size_t OFF_XN  = OFF_K + SZ_K;
  constexpr size_t SZ_XN   = (size_t)8224 * DM * 2;
  constexpr size_t OFF_W4  = OFF_XN + SZ_XN;
  constexpr size_t SZ_DD   = (size_t)DM * DM * 2;
  constexpr size_t OFF_XB  = OFF_W4 + 4 * SZ_DD;
  constexpr size_t SZ_XB   = (size_t)NB * SEQ * DM * 2;
  constexpr size_t OFF_SM  = OFF_XB + SZ_XB;
  static_assert(OFF_XN + (size_t)NB * SEQ * 2048 * 2 <= OFF_SM, "h1 overlay");
  static_assert(OFF_Q + (size_t)NB * SEQ * DM * 4 <= OFF_XN, "x1f overlay");

  unsigned short* Wt1 = (unsigned short*)(ws + OFF_WT1);
  unsigned short* Wt2 = (unsigned short*)(ws + OFF_WT2);
  unsigned short* Vtb = (unsigned short*)(ws + OFF_VT);
  unsigned short* Qb  = (unsigned short*)(ws + OFF_Q);
  unsigned short* Kbf = (unsigned short*)(ws + OFF_K);
  unsigned short* xn  = (unsigned short*)(ws + OFF_XN);
  unsigned short* Wtq = (unsigned short*)(ws + OFF_W4);
  unsigned short* Wtk = (unsigned short*)(ws + OFF_W4 + SZ_DD);
  unsigned short* Wtv = (unsigned short*)(ws + OFF_W4 + 2 * SZ_DD);
  unsigned short* Wto = (unsigned short*)(ws + OFF_W4 + 3 * SZ_DD);
  unsigned short* xb  = (unsigned short*)(ws + OFF_XB);
  unsigned short* MT  = (unsigned short*)(ws + OFF_SM);
  unsigned short* L1A = (unsigned short*)(ws + OFF_SM + 65536);
  unsigned short* L1B = (unsigned short*)(ws + OFF_SM + 67584);
  unsigned short* L2A = (unsigned short*)(ws + OFF_SM + 69632);
  unsigned short* L2B = (unsigned short*)(ws + OFF_SM + 71680);
  unsigned short* FB1 = (unsigned short*)(ws + OFF_SM + 73728);
  unsigned short* FB2 = (unsigned short*)(ws + OFF_SM + 81920);
  float*          accb= (float*)(ws + OFF_SM + 84480);
  int*            FLAG= (int*)(ws + OFF_SM + 101376);

  unsigned short* ctx = xn;
  unsigned short* h1  = xn;
  float*          x1f = (float*)(ws + OFF_Q);
  unsigned short* xn2 = Vtb;

  const dim3 blk(256);

  prep<<<PREP_T, blk, 0, stream>>>(x, memtok, wq, wk, wv, wo, fw1, fw2,
                                   ln1a, ln1b, ln2a, ln2b, fb1, fb2,
                                   xb, MT, Wtq, Wtk, Wtv, Wto, Wt1, Wt2,
                                   L1A, L1B, L2A, L2B, FB1, FB2, FLAG);

  ln_kernel<<<8224, blk, 0, stream>>>(xb, nullptr, MT, L1A, L1B, xn, 8192);

  // merged QKV: Bt rows [0,1024)=Wtq [1024,2048)=Wtk [2048,3072)=Wtv
  gemm_bt<<<dim3(24, 65), blk, 0, stream>>>(
      xn, DM, Wtq, DM, nullptr, nullptr, nullptr,
      Qb, Kbf, Vtb, 8224, 3072, DM, 0, 5, nullptr);
  replicate_mem<<<128, blk, 0, stream>>>(Kbf, Vtb);

  flash_attn<<<1024, blk, 0, stream>>>(Qb, Kbf, Vtb, ctx);

  gemm_bt<<<dim3(8, 64), blk, 0, stream>>>(
      ctx, DM, Wto, DM, nullptr, xb, nullptr,
      x1f, nullptr, nullptr, 8192, DM, DM, 0, 3, nullptr);

  ln_kernel<<<8192, blk, 0, stream>>>(nullptr, x1f, nullptr, L2A, L2B, xn2, 8192);

  gemm_bt<<<dim3(16, 64), blk, 0, stream>>>(
      xn2, DM, Wt1, DM, FB1, nullptr, nullptr,
      h1, nullptr, nullptr, 8192, 2048, DM, 1, 0, nullptr);
  gemm_bt<<<dim3(8, 64), blk, 0, stream>>>(
      h1, 2048, Wt2, DFF, nullptr, nullptr, x1f,
      x1f, nullptr, nullptr, 8192, DM, 2048, 0, 3, nullptr);
  gemm_bt<<<dim3(16, 64), blk, 0, stream>>>(
      xn2, DM, Wt1 + (size_t)2048 * DM, DM, FB1 + 2048, nullptr, nullptr,
      h1, nullptr, nullptr, 8192, 2048, DM, 1, 0, nullptr);
  gemm_bt<<<dim3(8, 64), blk, 0, stream>>>(
      h1, 2048, Wt2 + 2048, DFF, FB2, nullptr, x1f,
      d_out, nullptr, nullptr, 8192, DM, 2048, 0, 4, FLAG);

  hipMemsetAsync(accb, 0, (size_t)NB * DM * sizeof(float), stream);
  colsum<<<dim3(4, 8, 4), blk, 0, stream>>>(d_out, accb, FLAG);
  write_mem<<<16, blk, 0, stream>>>(accb, d_out, FLAG);
}

// Round 8
// 630.946 us; speedup vs baseline: 1.1045x; 1.1045x over previous
//
#include <hip/hip_runtime.h>
#include <hip/hip_bf16.h>
#include <cstdint>
#include <cstddef>

// ---------------------------------------------------------------------------
// EncoderBlockWithMemory on MI355X (gfx950). bf16-or-fp32 inputs (runtime
// detect), bf16 MFMA math, fp32 accumulate.
// R13: gemm reverted to R11 exactly (648.7us best: BK=32 dbuf, vmcnt(4),
// (256,3), merged-QKV). R12's 3-deep prefetch regressed (mod-3 indexing
// defeats LDS addr folding; latency already TLP-covered) - retired.
// flash_attn: SWAPPED QK^T (mfma(K,Q) - free, A/B fragments have identical
// lane maps) makes each lane hold 4 CONSECUTIVE k of P for its q-row ->
// softmax spill becomes 8x ds_write_b64 + 16x v_cvt_pk_bf16_f32 per tile
// instead of 32x scalar ds_write_b16 + 64 cvt VALU ops + 32 addr calcs.
// PV/Osum/epilogue unchanged (same Ps[q][k] layout).
// ---------------------------------------------------------------------------

typedef __attribute__((ext_vector_type(8))) short short8;
typedef __attribute__((ext_vector_type(4))) float floatx4;
typedef __attribute__((ext_vector_type(4))) unsigned short ushort4v;
typedef __attribute__((ext_vector_type(2))) unsigned int uint2v;

#define NB   4
#define SEQ  2048
#define DM   1024
#define DKH  64
#define TT   2080
#define DFF  4096
#define NMEM 32

static __device__ __forceinline__ float bu2f(unsigned short u) {
  return __uint_as_float(((unsigned int)u) << 16);
}
static __device__ __forceinline__ unsigned short f2bu(float x) {
  __hip_bfloat16 h = __float2bfloat16(x);
  return *reinterpret_cast<unsigned short*>(&h);
}
static __device__ __forceinline__ float fast_exp2(float x) {
#if __has_builtin(__builtin_amdgcn_exp2f)
  return __builtin_amdgcn_exp2f(x);
#else
  return exp2f(x);
#endif
}
static __device__ __forceinline__ void async16(const void* g, void* l) {
  __builtin_amdgcn_global_load_lds(
      (const __attribute__((address_space(1))) void*)g,
      (__attribute__((address_space(3))) void*)l, 16, 0, 0);
}

// --------------------------- merged prep kernel ----------------------------
#define PREP_X   8192
#define PREP_MT  (PREP_X + 32)
#define PREP_SM  (PREP_MT + 9)
#define PREP_T   (PREP_SM + 3072)

__global__ __launch_bounds__(256) void prep(
    const void* __restrict__ x,   const void* __restrict__ memtok,
    const void* __restrict__ wq,  const void* __restrict__ wk,
    const void* __restrict__ wv,  const void* __restrict__ wo,
    const void* __restrict__ fw1, const void* __restrict__ fw2,
    const void* __restrict__ ln1a, const void* __restrict__ ln1b,
    const void* __restrict__ ln2a, const void* __restrict__ ln2b,
    const void* __restrict__ fb1, const void* __restrict__ fb2,
    unsigned short* __restrict__ xb, unsigned short* __restrict__ MT,
    unsigned short* __restrict__ Wtq, unsigned short* __restrict__ Wtk,
    unsigned short* __restrict__ Wtv, unsigned short* __restrict__ Wto,
    unsigned short* __restrict__ Wt1, unsigned short* __restrict__ Wt2,
    unsigned short* __restrict__ L1A, unsigned short* __restrict__ L1B,
    unsigned short* __restrict__ L2A, unsigned short* __restrict__ L2B,
    unsigned short* __restrict__ FB1, unsigned short* __restrict__ FB2,
    int* __restrict__ FLAG)
{
  const int tid = threadIdx.x;
  const unsigned short probe = ((const unsigned short*)x)[tid & 63];
  const unsigned e = (probe >> 7) & 0xFF;
  const bool ok = (e == 0) || (e >= 100 && e <= 141);
  const int flag = (__ballot(!ok) != 0ULL) ? 1 : 0;
  const int bid = blockIdx.x;
  if (bid == 0 && tid == 0) *FLAG = flag;

  if (bid < PREP_T && bid >= PREP_SM) {
    const int tb = bid - PREP_SM;
    const void* in; unsigned short* outp; int R, C, tx, ty;
    if (tb < 1024) {
      const int w = tb >> 8, lt = tb & 255;
      in = (w == 0) ? wq : (w == 1) ? wk : (w == 2) ? wv : wo;
      outp = (w == 0) ? Wtq : (w == 1) ? Wtk : (w == 2) ? Wtv : Wto;
      R = DM; C = DM; tx = lt & 15; ty = lt >> 4;
    } else if (tb < 2048) {
      const int lt = tb - 1024;
      in = fw1; outp = Wt1; R = DM; C = DFF; tx = lt & 63; ty = lt >> 6;
    } else {
      const int lt = tb - 2048;
      in = fw2; outp = Wt2; R = DFF; C = DM; tx = lt & 15; ty = lt >> 4;
    }
    __shared__ unsigned short tile[64][65];
    const int r0 = ty << 6, c0 = tx << 6;
    const int lr = tid >> 2, lc = (tid & 3) << 4;
    if (flag) {
      const float* ip = (const float*)in + (size_t)(r0 + lr) * C + c0 + lc;
#pragma unroll
      for (int q = 0; q < 16; q += 4) {
        floatx4 f = *(const floatx4*)(ip + q);
        tile[lr][lc+q+0] = f2bu(f[0]); tile[lr][lc+q+1] = f2bu(f[1]);
        tile[lr][lc+q+2] = f2bu(f[2]); tile[lr][lc+q+3] = f2bu(f[3]);
      }
    } else {
      const unsigned short* ip = (const unsigned short*)in + (size_t)(r0 + lr) * C + c0 + lc;
#pragma unroll
      for (int q = 0; q < 16; q += 4) {
        ushort4v a = *(const ushort4v*)(ip + q);
        tile[lr][lc+q+0] = a.x; tile[lr][lc+q+1] = a.y;
        tile[lr][lc+q+2] = a.z; tile[lr][lc+q+3] = a.w;
      }
    }
    __syncthreads();
    unsigned short* op = outp + (size_t)(c0 + lr) * R + r0 + lc;
#pragma unroll
    for (int q = 0; q < 16; q += 4) {
      ushort4v a;
      a.x = tile[lc+q+0][lr]; a.y = tile[lc+q+1][lr];
      a.z = tile[lc+q+2][lr]; a.w = tile[lc+q+3][lr];
      *(ushort4v*)(op + q) = a;
    }
    return;
  }

  const void* src; unsigned short* dst; int base;
  if (bid < PREP_X)      { src = x;      dst = xb; base = bid * 1024; }
  else if (bid < PREP_MT){ src = memtok; dst = MT; base = (bid - PREP_X) * 1024; }
  else {
    const int s = bid - PREP_MT; base = 0;
    if      (s == 0) { src = ln1a; dst = L1A; }
    else if (s == 1) { src = ln1b; dst = L1B; }
    else if (s == 2) { src = ln2a; dst = L2A; }
    else if (s == 3) { src = ln2b; dst = L2B; }
    else if (s <= 7) { src = fb1;  dst = FB1; base = (s - 4) * 1024; }
    else             { src = fb2;  dst = FB2; }
  }
  const int i = base + tid * 4;
  if (flag) {
    const float* s4 = (const float*)src + i;
    ushort4v o;
    o.x = f2bu(s4[0]); o.y = f2bu(s4[1]); o.z = f2bu(s4[2]); o.w = f2bu(s4[3]);
    *(ushort4v*)&dst[i] = o;
  } else {
    *(ushort4v*)&dst[i] = *(const ushort4v*)&((const unsigned short*)src)[i];
  }
}

// ---------------------------------------------------------------------------
// gemm_bt (R11-verified, 648.7us config): C[M,N] = A[M,K](lda) @ Bt[N,K]^T
// (+bias)(relu)(+resid). BK=32, 128x128 tile, 4 waves, LDS double-buffer,
// counted vmcnt(4), chunk-XOR swizzle, XCD-chunked remap (nwg%8==0),
// __launch_bounds__(256,3) -> 3 blocks/CU.
// modes: 0 bf16 out  3 fp32 out  4 final d_out (dtype per *dt)
//        5 merged QKV col-sector epilogue (Q plain / K remap / V^T remap)
// ---------------------------------------------------------------------------
__global__ __launch_bounds__(256, 3) void gemm_bt(
    const unsigned short* __restrict__ A, int lda,
    const unsigned short* __restrict__ Bt, int ldbt,
    const unsigned short* __restrict__ bias,
    const unsigned short* __restrict__ resid_b,
    const float* __restrict__ resid_f,
    void* __restrict__ outp, void* __restrict__ outp2, void* __restrict__ outp3,
    int M, int N, int K, int relu, int mode, const int* __restrict__ dt)
{
  __shared__ __align__(16) unsigned short As[2][128 * 32];
  __shared__ __align__(16) unsigned short Bs[2][128 * 32];

  const int tid  = threadIdx.x;
  const int wave = tid >> 6;
  const int lane = tid & 63;
  const int quad = lane >> 4;
  const int lr   = lane & 15;
  const int wm   = (wave >> 1) * 64;
  const int wn   = (wave & 1) * 64;

  const int gx  = gridDim.x;
  const int nwg = gx * gridDim.y;
  int wg = blockIdx.y * gx + blockIdx.x;
  wg = (wg & 7) * (nwg >> 3) + (wg >> 3);
  const int by = wg / gx;
  const int bx = wg - by * gx;
  const int m0 = by * 128;
  const int n0 = bx * 128;

  floatx4 acc[4][4];
#pragma unroll
  for (int i = 0; i < 4; ++i)
#pragma unroll
    for (int j = 0; j < 4; ++j) { floatx4 z = {0.f, 0.f, 0.f, 0.f}; acc[i][j] = z; }

  const int srow = lane >> 2;
  const int skof = (((lane & 3) ^ ((lane >> 3) & 3))) * 8;
  const int fsw  = (lr >> 1) & 3;

  auto stage = [&](int buf, int kk) {
#pragma unroll
    for (int i = 0; i < 2; ++i) {
      const int rr = wave * 32 + i * 16;
      const int r  = rr + srow;
      int gr = m0 + r; gr = gr < M ? gr : (M - 1);
      async16(A  + (size_t)gr * lda + kk + skof, &As[buf][rr * 32]);
      const int gn = n0 + r;
      async16(Bt + (size_t)gn * ldbt + kk + skof, &Bs[buf][rr * 32]);
    }
  };

  const int nk = K >> 5;
  stage(0, 0);
  int cur = 0;
  for (int it = 0; it < nk; ++it) {
    if (it + 1 < nk) {
      stage(cur ^ 1, (it + 1) << 5);
      asm volatile("s_waitcnt vmcnt(4)" ::: "memory");
    } else {
      asm volatile("s_waitcnt vmcnt(0)" ::: "memory");
    }
    __builtin_amdgcn_s_barrier();

    const unsigned short* Ab = &As[cur][0];
    const unsigned short* Bb = &Bs[cur][0];
    short8 af[4], bfr[4];
#pragma unroll
    for (int mi = 0; mi < 4; ++mi)
      af[mi]  = *(const short8*)&Ab[(wm + mi * 16 + lr) * 32 + ((quad ^ fsw) * 8)];
#pragma unroll
    for (int ni = 0; ni < 4; ++ni)
      bfr[ni] = *(const short8*)&Bb[(wn + ni * 16 + lr) * 32 + ((quad ^ fsw) * 8)];
#pragma unroll
    for (int mi = 0; mi < 4; ++mi)
#pragma unroll
      for (int ni = 0; ni < 4; ++ni)
        acc[mi][ni] = __builtin_amdgcn_mfma_f32_16x16x32_bf16(af[mi], bfr[ni], acc[mi][ni], 0, 0, 0);

    asm volatile("s_waitcnt lgkmcnt(0)" ::: "memory");
    __builtin_amdgcn_s_barrier();
    cur ^= 1;
  }

  if (mode == 5) {
    const int cb     = n0 + wn;
    const int sector = cb >> 10;
    const int clb    = cb & 1023;
    unsigned short* Qo = (unsigned short*)outp;
    unsigned short* Ko = (unsigned short*)outp2;
    unsigned short* Vo = (unsigned short*)outp3;
#pragma unroll
    for (int mi = 0; mi < 4; ++mi) {
      const int rb = m0 + wm + mi * 16 + quad * 4;
#pragma unroll
      for (int ni = 0; ni < 4; ++ni) {
        const int col = clb + ni * 16 + lr;
        if (sector == 0) {
#pragma unroll
          for (int rg = 0; rg < 4; ++rg) {
            const int r = rb + rg;
            if (r < NB * SEQ) Qo[(size_t)r * DM + col] = f2bu(acc[mi][ni][rg]);
          }
        } else if (sector == 1) {
#pragma unroll
          for (int rg = 0; rg < 4; ++rg) {
            const int r = rb + rg;
            if (r >= M) continue;
            const int row2 = (r < NB * SEQ) ? ((r >> 11) * TT + NMEM + (r & (SEQ - 1)))
                                            : (r - NB * SEQ);
            Ko[(size_t)row2 * DM + col] = f2bu(acc[mi][ni][rg]);
          }
        } else {
          if (rb < M) {
            int bb, t;
            if (rb < NB * SEQ) { bb = rb >> 11; t = NMEM + (rb & (SEQ - 1)); }
            else               { bb = 0;        t = rb - NB * SEQ; }
            ushort4v pk;
            pk.x = f2bu(acc[mi][ni][0]); pk.y = f2bu(acc[mi][ni][1]);
            pk.z = f2bu(acc[mi][ni][2]); pk.w = f2bu(acc[mi][ni][3]);
            *(ushort4v*)(Vo + ((size_t)bb * DM + col) * TT + t) = pk;
          }
        }
      }
    }
    return;
  }

  const int ofp32 = (mode == 4 && dt) ? *dt : 0;
#pragma unroll
  for (int mi = 0; mi < 4; ++mi) {
    const int rb = m0 + wm + mi * 16 + quad * 4;
#pragma unroll
    for (int ni = 0; ni < 4; ++ni) {
      const int col = n0 + wn + ni * 16 + lr;
      const float bv = bias ? bu2f(bias[col]) : 0.0f;
#pragma unroll
      for (int rg = 0; rg < 4; ++rg) {
        const int r = rb + rg;
        if (r >= M) continue;
        float v = acc[mi][ni][rg] + bv;
        if (relu) v = fmaxf(v, 0.0f);
        if (resid_b) v += bu2f(resid_b[(size_t)r * N + col]);
        if (resid_f) v += resid_f[(size_t)r * N + col];
        const size_t idx = (size_t)r * N + col;
        if (mode == 3)       ((float*)outp)[idx] = v;
        else if (mode == 4) {
          if (ofp32) ((float*)outp)[idx] = v;
          else       ((unsigned short*)outp)[idx] = f2bu(v);
        } else               ((unsigned short*)outp)[idx] = f2bu(v);
      }
    }
  }
}

// ---------------------------------------------------------------------------
// Flash attention R13: swapped QK^T -> packed Ps writes.
// QK^T computed as mfma(K_frag, Q_frag) (operand swap is free: A/B fragment
// lane maps are identical) so lane holds S^T: q=lr, k=ni*16+quad*4+rg -- 4
// CONSECUTIVE k per q-row. Softmax spill = 2x v_cvt_pk_bf16_f32 + 1x
// ds_write_b64 per (mi,ni) into the same Ps[q][k] layout. PV/Osum/epilogue
// unchanged. K/V double-buffer + counted vmcnt(4) + setprio (R8-verified).
// ---------------------------------------------------------------------------
#define PSTR 72

__global__ __launch_bounds__(256, 3) void flash_attn(
    const unsigned short* __restrict__ Q,
    const unsigned short* __restrict__ Kb,
    const unsigned short* __restrict__ Vtb,
    unsigned short* __restrict__ ctx)
{
  __shared__ __align__(16) unsigned short Ks[2][64 * 64];
  __shared__ __align__(16) unsigned short Vs[2][64 * 64];
  __shared__ __align__(16) unsigned short Ps[128 * PSTR];

  const int tid  = threadIdx.x;
  const int wave = tid >> 6;
  const int lane = tid & 63;
  const int quad = lane >> 4;
  const int lr   = lane & 15;

  const int i    = blockIdx.x;
  const int pair = (i & 7) * 8 + (i >> 7);
  const int q0   = ((i >> 3) & 15) * 128;
  const int b    = pair >> 4;
  const int h    = pair & 15;

  const unsigned short* Qb  = Q   + ((size_t)(b * SEQ + q0)) * DM + h * DKH;
  const unsigned short* Kbp = Kb  + ((size_t)b * TT) * DM + h * DKH;
  const unsigned short* Vbp = Vtb + ((size_t)(b * DM + h * DKH)) * TT;

  short8 aq[2][2];
#pragma unroll
  for (int mi = 0; mi < 2; ++mi)
#pragma unroll
    for (int ks = 0; ks < 2; ++ks)
      aq[mi][ks] = *(const short8*)(Qb + (size_t)(wave * 32 + mi * 16 + lr) * DM
                                       + ks * 32 + quad * 8);

  const int srl = lane >> 3;
  const int swc = (lane & 7) ^ srl;

  floatx4 O[2][4], Osum[2];
#pragma unroll
  for (int mi = 0; mi < 2; ++mi) {
    floatx4 z = {0.f, 0.f, 0.f, 0.f};
    Osum[mi] = z;
#pragma unroll
    for (int ni = 0; ni < 4; ++ni) O[mi][ni] = z;
  }
  short8 ones;
#pragma unroll
  for (int i2 = 0; i2 < 8; ++i2) ones[i2] = (short)0x3F80;

  const float SC = 0.125f * 1.4426950408889634f;

  auto stageKV = [&](int buf, int t0s) {
#pragma unroll
    for (int i2 = 0; i2 < 2; ++i2) {
      const int rr = (wave * 2 + i2) * 8 + srl;
      int tg = t0s + rr; tg = tg < TT ? tg : (TT - 1);
      async16(Kbp + (size_t)tg * DM + swc * 8, &Ks[buf][(wave * 2 + i2) * 512]);
      int ts = t0s + swc * 8; ts = ts <= (TT - 8) ? ts : (TT - 8);
      async16(Vbp + (size_t)rr * TT + ts, &Vs[buf][(wave * 2 + i2) * 512]);
    }
  };

  stageKV(0, 0);
  int cur = 0;

  for (int t0 = 0; t0 < TT; t0 += 64) {
    if (t0 + 64 < TT) {
      stageKV(cur ^ 1, t0 + 64);
      asm volatile("s_waitcnt vmcnt(4)" ::: "memory");
    } else {
      asm volatile("s_waitcnt vmcnt(0)" ::: "memory");
    }
    __builtin_amdgcn_s_barrier();

    // swapped QK^T: sc4[mi][ni] = S^T fragment, q=lr, k=ni*16+quad*4+rg
    floatx4 sc4[2][4];
#pragma unroll
    for (int mi = 0; mi < 2; ++mi)
#pragma unroll
      for (int ni = 0; ni < 4; ++ni) { floatx4 z = {0.f, 0.f, 0.f, 0.f}; sc4[mi][ni] = z; }
#pragma unroll
    for (int ks = 0; ks < 2; ++ks) {
      short8 bk[4];
#pragma unroll
      for (int ni = 0; ni < 4; ++ni) {
        const int row = ni * 16 + lr;
        bk[ni] = *(const short8*)&Ks[cur][row * 64 + (((ks * 4 + quad) ^ (row & 7)) * 8)];
      }
      __builtin_amdgcn_s_setprio(1);
#pragma unroll
      for (int mi = 0; mi < 2; ++mi)
#pragma unroll
        for (int ni = 0; ni < 4; ++ni)
          sc4[mi][ni] = __builtin_amdgcn_mfma_f32_16x16x32_bf16(bk[ni], aq[mi][ks], sc4[mi][ni], 0, 0, 0);
      __builtin_amdgcn_s_setprio(0);
    }

    // softmax + packed spill: p = exp2(s*SC) masked by k < TT-t0;
    // 4 consecutive k per (mi,ni) -> 2 cvt_pk + 1 ds_write_b64
    const int rem = TT - t0;   // 64 normally, 32 on last tile
#pragma unroll
    for (int mi = 0; mi < 2; ++mi) {
      const int prow = (wave * 32 + mi * 16 + lr) * PSTR;
#pragma unroll
      for (int ni = 0; ni < 4; ++ni) {
        const int kb = ni * 16 + quad * 4;
        float p0 = (kb + 0 < rem) ? fast_exp2(sc4[mi][ni][0] * SC) : 0.0f;
        float p1 = (kb + 1 < rem) ? fast_exp2(sc4[mi][ni][1] * SC) : 0.0f;
        float p2 = (kb + 2 < rem) ? fast_exp2(sc4[mi][ni][2] * SC) : 0.0f;
        float p3 = (kb + 3 < rem) ? fast_exp2(sc4[mi][ni][3] * SC) : 0.0f;
        unsigned int u0, u1;
        asm("v_cvt_pk_bf16_f32 %0, %1, %2" : "=v"(u0) : "v"(p0), "v"(p1));
        asm("v_cvt_pk_bf16_f32 %0, %1, %2" : "=v"(u1) : "v"(p2), "v"(p3));
        uint2v pk2; pk2.x = u0; pk2.y = u1;
        *(uint2v*)&Ps[prow + kb] = pk2;
      }
    }

    __asm__ __volatile__("" ::: "memory");

#pragma unroll
    for (int ks = 0; ks < 2; ++ks) {
      short8 ap[2], bv[4];
#pragma unroll
      for (int mi = 0; mi < 2; ++mi)
        ap[mi] = *(const short8*)&Ps[(wave * 32 + mi * 16 + lr) * PSTR + ks * 32 + quad * 8];
#pragma unroll
      for (int ni = 0; ni < 4; ++ni) {
        const int row = ni * 16 + lr;
        bv[ni] = *(const short8*)&Vs[cur][row * 64 + (((ks * 4 + quad) ^ (row & 7)) * 8)];
      }
      __builtin_amdgcn_s_setprio(1);
#pragma unroll
      for (int mi = 0; mi < 2; ++mi) {
        Osum[mi] = __builtin_amdgcn_mfma_f32_16x16x32_bf16(ap[mi], ones, Osum[mi], 0, 0, 0);
#pragma unroll
        for (int ni = 0; ni < 4; ++ni)
          O[mi][ni] = __builtin_amdgcn_mfma_f32_16x16x32_bf16(ap[mi], bv[ni], O[mi][ni], 0, 0, 0);
      }
      __builtin_amdgcn_s_setprio(0);
    }

    asm volatile("s_waitcnt lgkmcnt(0)" ::: "memory");
    __builtin_amdgcn_s_barrier();
    cur ^= 1;
  }

#pragma unroll
  for (int mi = 0; mi < 2; ++mi)
#pragma unroll
    for (int rg = 0; rg < 4; ++rg) {
      const float inv = 1.0f / Osum[mi][rg];
      const int row = q0 + wave * 32 + mi * 16 + quad * 4 + rg;
#pragma unroll
      for (int ni = 0; ni < 4; ++ni) {
        const int col = h * DKH + ni * 16 + lr;
        ctx[((size_t)(b * SEQ + row)) * DM + col] = f2bu(O[mi][ni][rg] * inv);
      }
    }
}

// ---------------------------------------------------------------------------
__global__ __launch_bounds__(256) void ln_kernel(
    const unsigned short* __restrict__ xin_bf,
    const float* __restrict__ xin_f,
    const unsigned short* __restrict__ memtok,
    const unsigned short* __restrict__ gam,
    const unsigned short* __restrict__ bet,
    unsigned short* __restrict__ outp,
    int rows_main)
{
  const int row = blockIdx.x;
  const int tid = threadIdx.x;
  const int c0  = tid * 4;
  if (row >= rows_main) {
    const int mr = row - rows_main;
    *(ushort4v*)&outp[(size_t)row * DM + c0] =
        *(const ushort4v*)&memtok[(size_t)mr * DM + c0];
    return;
  }
  float v[4];
  if (xin_bf) {
    ushort4v u = *(const ushort4v*)&xin_bf[(size_t)row * DM + c0];
    v[0] = bu2f(u.x); v[1] = bu2f(u.y); v[2] = bu2f(u.z); v[3] = bu2f(u.w);
  } else {
    floatx4 f = *(const floatx4*)&xin_f[(size_t)row * DM + c0];
    v[0] = f[0]; v[1] = f[1]; v[2] = f[2]; v[3] = f[3];
  }
  float s  = v[0] + v[1] + v[2] + v[3];
  float ss = v[0]*v[0] + v[1]*v[1] + v[2]*v[2] + v[3]*v[3];
#pragma unroll
  for (int m = 1; m <= 32; m <<= 1) {
    s  += __shfl_xor(s, m, 64);
    ss += __shfl_xor(ss, m, 64);
  }
  __shared__ float red[8];
  const int wave = tid >> 6, lane = tid & 63;
  if (lane == 0) { red[wave] = s; red[4 + wave] = ss; }
  __syncthreads();
  s  = red[0] + red[1] + red[2] + red[3];
  ss = red[4] + red[5] + red[6] + red[7];
  const float mean = s * (1.0f / 1024.0f);
  float var = (ss - 1024.0f * mean * mean) * (1.0f / 1023.0f);
  var = fmaxf(var, 0.0f);
  const float inv = 1.0f / (sqrtf(var) + 1e-6f);
  ushort4v o;
  o.x = f2bu(bu2f(gam[c0+0]) * (v[0] - mean) * inv + bu2f(bet[c0+0]));
  o.y = f2bu(bu2f(gam[c0+1]) * (v[1] - mean) * inv + bu2f(bet[c0+1]));
  o.z = f2bu(bu2f(gam[c0+2]) * (v[2] - mean) * inv + bu2f(bet[c0+2]));
  o.w = f2bu(bu2f(gam[c0+3]) * (v[3] - mean) * inv + bu2f(bet[c0+3]));
  *(ushort4v*)&outp[(size_t)row * DM + c0] = o;
}

__global__ __launch_bounds__(256) void replicate_mem(
    unsigned short* __restrict__ Kb, unsigned short* __restrict__ Vtb)
{
  const int idx = blockIdx.x * 256 + threadIdx.x;
  const int t = idx >> 10, c = idx & 1023;
  const unsigned short kv = Kb[(size_t)t * DM + c];
  const unsigned short vv = Vtb[(size_t)c * TT + t];
#pragma unroll
  for (int b = 1; b < NB; ++b) {
    Kb[((size_t)b * TT + t) * DM + c] = kv;
    Vtb[((size_t)(b * DM + c)) * TT + t] = vv;
  }
}

__global__ __launch_bounds__(256) void colsum(
    const void* __restrict__ xo, float* __restrict__ acc,
    const int* __restrict__ flag)
{
  const int d  = blockIdx.x * 256 + threadIdx.x;
  const int s0 = blockIdx.y * 256;
  const int b  = blockIdx.z;
  const size_t base = ((size_t)(b * SEQ + s0)) * DM + d;
  float s = 0.0f;
  if (*flag) {
    const float* p = (const float*)xo;
    for (int i = 0; i < 256; ++i) s += p[base + (size_t)i * DM];
  } else {
    const unsigned short* p = (const unsigned short*)xo;
    for (int i = 0; i < 256; ++i) s += bu2f(p[base + (size_t)i * DM]);
  }
  atomicAdd(&acc[b * DM + d], s);
}

__global__ __launch_bounds__(256) void write_mem(
    const float* __restrict__ acc, void* __restrict__ dout,
    const int* __restrict__ flag)
{
  const int idx = blockIdx.x * 256 + threadIdx.x;
  const int b = idx >> 10, d = idx & 1023;
  const float w = acc[idx] * (1.0f / 2048.0f);
  const int f = *flag;
#pragma unroll
  for (int m = 0; m < NMEM; ++m) {
    const size_t off = (size_t)NB * SEQ * DM + ((size_t)(b * NMEM + m)) * DM + d;
    if (f) ((float*)dout)[off] = w;
    else   ((unsigned short*)dout)[off] = f2bu(w);
  }
}

// ---------------------------------------------------------------------------
extern "C" void kernel_launch(void* const* d_in, const int* in_sizes, int n_in,
                              void* d_out, int out_size, void* d_ws, size_t ws_size,
                              hipStream_t stream) {
  const void* x      = d_in[0];
  const void* memtok = d_in[2];
  const void* wq     = d_in[3];
  const void* wk     = d_in[4];
  const void* wv     = d_in[5];
  const void* wo     = d_in[6];
  const void* ln1a   = d_in[7];
  const void* ln1b   = d_in[8];
  const void* ln2a   = d_in[9];
  const void* ln2b   = d_in[10];
  const void* fw1    = d_in[11];
  const void* fb1    = d_in[12];
  const void* fw2    = d_in[13];
  const void* fb2    = d_in[14];

  char* ws = (char*)d_ws;
  constexpr size_t OFF_WT1 = 0;
  constexpr size_t OFF_WT2 = OFF_WT1 + (size_t)DFF * DM * 2;
  constexpr size_t OFF_VT  = OFF_WT2 + (size_t)DM * DFF * 2;
  constexpr size_t SZ_VT   = (size_t)NB * DM * TT * 2;
  constexpr size_t OFF_Q   = OFF_VT + SZ_VT;
  constexpr size_t SZ_Q    = (size_t)NB * SEQ * DM * 2;
  constexpr size_t OFF_K   = OFF_Q + SZ_Q;
  constexpr size_t SZ_K    = (size_t)NB * TT * DM * 2;
  constexpr size_t OFF_XN  = OFF_K + SZ_K;
  constexpr size_t SZ_XN   = (size_t)8224 * DM * 2;
  constexpr size_t OFF_W4  = OFF_XN + SZ_XN;
  constexpr size_t SZ_DD   = (size_t)DM * DM * 2;
  constexpr size_t OFF_XB  = OFF_W4 + 4 * SZ_DD;
  constexpr size_t SZ_XB   = (size_t)NB * SEQ * DM * 2;
  constexpr size_t OFF_SM  = OFF_XB + SZ_XB;
  static_assert(OFF_XN + (size_t)NB * SEQ * 2048 * 2 <= OFF_SM, "h1 overlay");
  static_assert(OFF_Q + (size_t)NB * SEQ * DM * 4 <= OFF_XN, "x1f overlay");

  unsigned short* Wt1 = (unsigned short*)(ws + OFF_WT1);
  unsigned short* Wt2 = (unsigned short*)(ws + OFF_WT2);
  unsigned short* Vtb = (unsigned short*)(ws + OFF_VT);
  unsigned short* Qb  = (unsigned short*)(ws + OFF_Q);
  unsigned short* Kbf = (unsigned short*)(ws + OFF_K);
  unsigned short* xn  = (unsigned short*)(ws + OFF_XN);
  unsigned short* Wtq = (unsigned short*)(ws + OFF_W4);
  unsigned short* Wtk = (unsigned short*)(ws + OFF_W4 + SZ_DD);
  unsigned short* Wtv = (unsigned short*)(ws + OFF_W4 + 2 * SZ_DD);
  unsigned short* Wto = (unsigned short*)(ws + OFF_W4 + 3 * SZ_DD);
  unsigned short* xb  = (unsigned short*)(ws + OFF_XB);
  unsigned short* MT  = (unsigned short*)(ws + OFF_SM);
  unsigned short* L1A = (unsigned short*)(ws + OFF_SM + 65536);
  unsigned short* L1B = (unsigned short*)(ws + OFF_SM + 67584);
  unsigned short* L2A = (unsigned short*)(ws + OFF_SM + 69632);
  unsigned short* L2B = (unsigned short*)(ws + OFF_SM + 71680);
  unsigned short* FB1 = (unsigned short*)(ws + OFF_SM + 73728);
  unsigned short* FB2 = (unsigned short*)(ws + OFF_SM + 81920);
  float*          accb= (float*)(ws + OFF_SM + 84480);
  int*            FLAG= (int*)(ws + OFF_SM + 101376);

  unsigned short* ctx = xn;
  unsigned short* h1  = xn;
  float*          x1f = (float*)(ws + OFF_Q);
  unsigned short* xn2 = Vtb;

  const dim3 blk(256);

  prep<<<PREP_T, blk, 0, stream>>>(x, memtok, wq, wk, wv, wo, fw1, fw2,
                                   ln1a, ln1b, ln2a, ln2b, fb1, fb2,
                                   xb, MT, Wtq, Wtk, Wtv, Wto, Wt1, Wt2,
                                   L1A, L1B, L2A, L2B, FB1, FB2, FLAG);

  ln_kernel<<<8224, blk, 0, stream>>>(xb, nullptr, MT, L1A, L1B, xn, 8192);

  // merged QKV: Bt rows [0,1024)=Wtq [1024,2048)=Wtk [2048,3072)=Wtv
  gemm_bt<<<dim3(24, 65), blk, 0, stream>>>(
      xn, DM, Wtq, DM, nullptr, nullptr, nullptr,
      Qb, Kbf, Vtb, 8224, 3072, DM, 0, 5, nullptr);
  replicate_mem<<<128, blk, 0, stream>>>(Kbf, Vtb);

  flash_attn<<<1024, blk, 0, stream>>>(Qb, Kbf, Vtb, ctx);

  gemm_bt<<<dim3(8, 64), blk, 0, stream>>>(
      ctx, DM, Wto, DM, nullptr, xb, nullptr,
      x1f, nullptr, nullptr, 8192, DM, DM, 0, 3, nullptr);

  ln_kernel<<<8192, blk, 0, stream>>>(nullptr, x1f, nullptr, L2A, L2B, xn2, 8192);

  gemm_bt<<<dim3(16, 64), blk, 0, stream>>>(
      xn2, DM, Wt1, DM, FB1, nullptr, nullptr,
      h1, nullptr, nullptr, 8192, 2048, DM, 1, 0, nullptr);
  gemm_bt<<<dim3(8, 64), blk, 0, stream>>>(
      h1, 2048, Wt2, DFF, nullptr, nullptr, x1f,
      x1f, nullptr, nullptr, 8192, DM, 2048, 0, 3, nullptr);
  gemm_bt<<<dim3(16, 64), blk, 0, stream>>>(
      xn2, DM, Wt1 + (size_t)2048 * DM, DM, FB1 + 2048, nullptr, nullptr,
      h1, nullptr, nullptr, 8192, 2048, DM, 1, 0, nullptr);
  gemm_bt<<<dim3(8, 64), blk, 0, stream>>>(
      h1, 2048, Wt2 + 2048, DFF, FB2, nullptr, x1f,
      d_out, nullptr, nullptr, 8192, DM, 2048, 0, 4, FLAG);

  hipMemsetAsync(accb, 0, (size_t)NB * DM * sizeof(float), stream);
  colsum<<<dim3(4, 8, 4), blk, 0, stream>>>(d_out, accb, FLAG);
  write_mem<<<16, blk, 0, stream>>>(accb, d_out, FLAG);
}